// Round 7
// baseline (419.159 us; speedup 1.0000x reference)
//
#include <hip/hip_runtime.h>
#include <math.h>

typedef short short8 __attribute__((ext_vector_type(8)));
typedef float f32x4 __attribute__((ext_vector_type(4)));

#define B_    2
#define HH    128
#define WW    128
#define NPIX  16384     // H*W
#define C_    384
#define CR    192
#define CG    128
#define NH    8
#define DK    24
#define HD    48
#define LL    1024      // 32*32 reduced tokens
#define KFUS  6144      // 16*384
// (hd*0.5)^-0.5 * log2(e)  — folded so P = exp2(S)
#define SCALE_L2E 0.29448889f

__device__ __forceinline__ float bf2f(short h) {
    union { unsigned u; float f; } v; v.u = ((unsigned)(unsigned short)h) << 16; return v.f;
}
__device__ __forceinline__ short f2bf(float f) {          // RNE
    union { float f; unsigned u; } v; v.f = f;
    unsigned r = v.u + 0x7fffu + ((v.u >> 16) & 1u);
    return (short)(unsigned short)(r >> 16);
}
__device__ __forceinline__ short f2bf_fast(float f) {     // round-nearest, ties-away
    union { float f; unsigned u; } v; v.f = f;
    return (short)(unsigned short)((v.u + 0x8000u) >> 16);
}
// 2^x via compiler-emitted v_exp_f32 (TRANS hazard handled by compiler;
// raw inline-asm v_exp_f32 caused nondeterministic stale reads in r2).
__device__ __forceinline__ float exp2b(float x) {
#if __has_builtin(__builtin_amdgcn_exp2f)
    return __builtin_amdgcn_exp2f(x);
#else
    return exp2f(x);
#endif
}
// pack bf16(lo) | bf16(hi) in one instruction (RNE). No builtin on gfx950.
// Regular VALU op (not TRANS) — guide T12 recipe, asm->MFMA path refcheck'd.
__device__ __forceinline__ unsigned cvt_pk_bf16(float lo, float hi) {
    unsigned r;
    asm("v_cvt_pk_bf16_f32 %0, %1, %2" : "=v"(r) : "v"(lo), "v"(hi));
    return r;
}

// ---------------------------------------------------------------------------
// Depthwise conv, one 128-channel group, 4 x-pixels per thread (x0 % 4 == 0).
// PATCH=0: fp32 flat out [B,NPIX,128].
// PATCH=1: bf16 im2col patch layout for the 4x4/stride4 conv.
// ---------------------------------------------------------------------------
template<int PATCH, int KS, int STRIDE>
__global__ __launch_bounds__(256) void dwconv_k(
    const float* __restrict__ in, int in_off,
    float* __restrict__ outf, short* __restrict__ outp, int out_coff,
    const float* __restrict__ w, const float* __restrict__ bias)
{
    constexpr int pad = KS / 2;
    constexpr int NV = 4 + KS - 1;
    int idx = blockIdx.x * 256 + threadIdx.x;   // 2*4096*128 total
    int c    = idx & (CG - 1);
    int pix4 = (idx >> 7) & 4095;
    int b    = idx >> 19;
    int y = pix4 >> 5, x0 = (pix4 & 31) << 2;
    float wl[KS * KS];
    #pragma unroll
    for (int i = 0; i < KS * KS; i++) wl[i] = w[c * KS * KS + i];
    float bv = bias[c];
    float acc[4] = {bv, bv, bv, bv};
    #pragma unroll
    for (int ky = 0; ky < KS; ky++) {
        int yy = y + ky - pad;
        if ((unsigned)yy >= HH) continue;
        const float* rowp = &in[(size_t)(b * NPIX + yy * WW) * STRIDE + in_off + c];
        float v[NV];
        #pragma unroll
        for (int j = 0; j < NV; j++) {
            int xx = x0 + j - pad;
            v[j] = ((unsigned)xx < WW) ? rowp[(size_t)xx * STRIDE] : 0.f;
        }
        #pragma unroll
        for (int kx = 0; kx < KS; kx++)
            #pragma unroll
            for (int o = 0; o < 4; o++)
                acc[o] += v[o + kx] * wl[ky * KS + kx];
    }
    if (!PATCH) {
        float* op = &outf[(size_t)(b * NPIX + y * WW + x0) * CG + c];
        #pragma unroll
        for (int o = 0; o < 4; o++) op[(size_t)o * CG] = acc[o];
    } else {
        int m = b * LL + (y >> 2) * 32 + (x0 >> 2);
        short* op = &outp[(size_t)m * KFUS + ((y & 3) * 4) * C_ + out_coff + c];
        #pragma unroll
        for (int o = 0; o < 4; o++) op[(size_t)o * C_] = f2bf(acc[o]);
    }
}

// ---------------------------------------------------------------------------
// Weight prep (fp32 -> bf16)
// ---------------------------------------------------------------------------
__global__ __launch_bounds__(256) void prep_k(
    const float* __restrict__ fus_w, const float* __restrict__ k_w,
    const float* __restrict__ v_w, const float* __restrict__ q_w,
    const float* __restrict__ proj_w,
    short* __restrict__ Wt, short* __restrict__ Bkv,
    short* __restrict__ qw_b, short* __restrict__ pw_b)
{
    int idx = blockIdx.x * 256 + threadIdx.x;
    const int NW = KFUS * CR;        // 1179648
    if (idx < NW) {
        int k = idx / CR, oc = idx - k * CR;
        int p = k / C_,  ic = k - p * C_;
        Wt[idx] = f2bf(fus_w[(oc * C_ + ic) * 16 + p]);
        return;
    }
    idx -= NW;
    if (idx < CR * 576) {            // 110592
        int k = idx / 576, n = idx - k * 576;
        Bkv[idx] = f2bf((n < CR) ? k_w[k * CR + n] : v_w[k * C_ + (n - CR)]);
        return;
    }
    idx -= CR * 576;
    if (idx < C_ * CR) { qw_b[idx] = f2bf(q_w[idx]); return; }
    idx -= C_ * CR;
    if (idx < C_ * C_) pw_b[idx] = f2bf(proj_w[idx]);
}

// ---------------------------------------------------------------------------
// Generic bf16 MFMA GEMM: C[M,N] = A[M,K] * B[K,N] (+bias)
// AF=1: A fp32 (converted on stage). CF=1: C written fp32.
// ---------------------------------------------------------------------------
template<int AF, int CF>
__global__ __launch_bounds__(256) void gemm_k(
    const void* __restrict__ Av, const short* __restrict__ Bm, void* __restrict__ Cv,
    const float* __restrict__ bias, int M, int N, int K)
{
    __shared__ short a_lds[64 * 40];
    __shared__ short bT_lds[64 * 40];
    int tid = threadIdx.x;
    int lane = tid & 63, wave = tid >> 6, quad = lane >> 4, l16 = lane & 15;
    int bm = blockIdx.x * 64, bn = blockIdx.y * 64;
    int wm = (wave >> 1) * 32, wn = (wave & 1) * 32;
    f32x4 z4 = {0.f, 0.f, 0.f, 0.f};
    f32x4 acc00 = z4, acc01 = z4, acc10 = z4, acc11 = z4;
    int arow = tid >> 2, aseg = tid & 3;
    int bk = tid >> 3, bnseg = tid & 7;

    for (int k0 = 0; k0 < K; k0 += 32) {
        __syncthreads();
        if (AF) {
            const float* Af = (const float*)Av;
            const float4* p = (const float4*)&Af[(size_t)(bm + arow) * K + k0 + aseg * 8];
            float4 f0 = p[0], f1 = p[1];
            short8 av;
            av[0] = f2bf_fast(f0.x); av[1] = f2bf_fast(f0.y);
            av[2] = f2bf_fast(f0.z); av[3] = f2bf_fast(f0.w);
            av[4] = f2bf_fast(f1.x); av[5] = f2bf_fast(f1.y);
            av[6] = f2bf_fast(f1.z); av[7] = f2bf_fast(f1.w);
            *(short8*)&a_lds[arow * 40 + aseg * 8] = av;
        } else {
            const short* Ab = (const short*)Av;
            *(short8*)&a_lds[arow * 40 + aseg * 8] =
                *(const short8*)&Ab[(size_t)(bm + arow) * K + k0 + aseg * 8];
        }
        short8 bv = *(const short8*)&Bm[(size_t)(k0 + bk) * N + bn + bnseg * 8];
        #pragma unroll
        for (int i = 0; i < 8; i++) bT_lds[(bnseg * 8 + i) * 40 + bk] = bv[i];
        __syncthreads();
        short8 a0 = *(short8*)&a_lds[(wm + l16) * 40 + quad * 8];
        short8 a1 = *(short8*)&a_lds[(wm + 16 + l16) * 40 + quad * 8];
        short8 b0 = *(short8*)&bT_lds[(wn + l16) * 40 + quad * 8];
        short8 b1 = *(short8*)&bT_lds[(wn + 16 + l16) * 40 + quad * 8];
        acc00 = __builtin_amdgcn_mfma_f32_16x16x32_bf16(a0, b0, acc00, 0, 0, 0);
        acc01 = __builtin_amdgcn_mfma_f32_16x16x32_bf16(a0, b1, acc01, 0, 0, 0);
        acc10 = __builtin_amdgcn_mfma_f32_16x16x32_bf16(a1, b0, acc10, 0, 0, 0);
        acc11 = __builtin_amdgcn_mfma_f32_16x16x32_bf16(a1, b1, acc11, 0, 0, 0);
    }
    f32x4 accs[2][2] = {{acc00, acc01}, {acc10, acc11}};
    #pragma unroll
    for (int mt = 0; mt < 2; mt++)
      #pragma unroll
      for (int nt = 0; nt < 2; nt++) {
        int col = bn + wn + nt * 16 + l16;
        float bvv = bias ? bias[col] : 0.f;
        #pragma unroll
        for (int r = 0; r < 4; r++) {
            int row = bm + wm + mt * 16 + quad * 4 + r;
            float v = accs[mt][nt][r] + bvv;
            if (CF) ((float*)Cv)[(size_t)row * N + col] = v;
            else    ((short*)Cv)[(size_t)row * N + col] = f2bf(v);
        }
      }
}

// ---------------------------------------------------------------------------
// Split-K GEMM for the fusion conv: fp32 partials per z-slice.
// ---------------------------------------------------------------------------
__global__ __launch_bounds__(256) void gemm_part_k(
    const short* __restrict__ A, const short* __restrict__ Bm,
    float* __restrict__ Cpart, int M, int N, int K, int kchunk)
{
    __shared__ short a_lds[64 * 40];
    __shared__ short bT_lds[64 * 40];
    int tid = threadIdx.x;
    int lane = tid & 63, wave = tid >> 6, quad = lane >> 4, l16 = lane & 15;
    int bm = blockIdx.x * 64, bn = blockIdx.y * 64;
    int kbeg = blockIdx.z * kchunk, kend = kbeg + kchunk;
    int wm = (wave >> 1) * 32, wn = (wave & 1) * 32;
    f32x4 z4 = {0.f, 0.f, 0.f, 0.f};
    f32x4 acc00 = z4, acc01 = z4, acc10 = z4, acc11 = z4;
    int arow = tid >> 2, aseg = tid & 3;
    int bk = tid >> 3, bnseg = tid & 7;

    for (int k0 = kbeg; k0 < kend; k0 += 32) {
        __syncthreads();
        *(short8*)&a_lds[arow * 40 + aseg * 8] =
            *(const short8*)&A[(size_t)(bm + arow) * K + k0 + aseg * 8];
        short8 bv = *(const short8*)&Bm[(size_t)(k0 + bk) * N + bn + bnseg * 8];
        #pragma unroll
        for (int i = 0; i < 8; i++) bT_lds[(bnseg * 8 + i) * 40 + bk] = bv[i];
        __syncthreads();
        short8 a0 = *(short8*)&a_lds[(wm + l16) * 40 + quad * 8];
        short8 a1 = *(short8*)&a_lds[(wm + 16 + l16) * 40 + quad * 8];
        short8 b0 = *(short8*)&bT_lds[(wn + l16) * 40 + quad * 8];
        short8 b1 = *(short8*)&bT_lds[(wn + 16 + l16) * 40 + quad * 8];
        acc00 = __builtin_amdgcn_mfma_f32_16x16x32_bf16(a0, b0, acc00, 0, 0, 0);
        acc01 = __builtin_amdgcn_mfma_f32_16x16x32_bf16(a0, b1, acc01, 0, 0, 0);
        acc10 = __builtin_amdgcn_mfma_f32_16x16x32_bf16(a1, b0, acc10, 0, 0, 0);
        acc11 = __builtin_amdgcn_mfma_f32_16x16x32_bf16(a1, b1, acc11, 0, 0, 0);
    }
    float* Cs = Cpart + (size_t)blockIdx.z * M * N;
    f32x4 accs[2][2] = {{acc00, acc01}, {acc10, acc11}};
    #pragma unroll
    for (int mt = 0; mt < 2; mt++)
      #pragma unroll
      for (int nt = 0; nt < 2; nt++) {
        int col = bn + wn + nt * 16 + l16;
        #pragma unroll
        for (int r = 0; r < 4; r++) {
            int row = bm + wm + mt * 16 + quad * 4 + r;
            Cs[(size_t)row * N + col] = accs[mt][nt][r];
        }
      }
}

// Reduce 4 split-K partials + bias + exact GELU -> bf16 xr [2048 x 192]
__global__ __launch_bounds__(256) void fusred_k(
    const float* __restrict__ part, const float* __restrict__ bias,
    short* __restrict__ xr)
{
    const int MN = 2048 * CR;
    int idx = blockIdx.x * 256 + threadIdx.x;
    float v = part[idx] + part[idx + MN] + part[idx + 2 * MN] + part[idx + 3 * MN]
            + bias[idx % CR];
    v = 0.5f * v * (1.f + erff(v * 0.70710678118f));
    xr[idx] = f2bf(v);
}

// ---------------------------------------------------------------------------
// CPE: v2[b,l,c] = v[b,l,c] + dwconv3x3(v as [B,C,32,32])[b,c,l] + cpe_b[c]
// r6: vectorized 8 channels/thread (short8 loads — consecutive c contiguous).
// ---------------------------------------------------------------------------
__global__ __launch_bounds__(256) void cpe_k(
    const short* __restrict__ kv, const float* __restrict__ cw,
    const float* __restrict__ cb, short* __restrict__ v2)
{
    int idx = blockIdx.x * 256 + threadIdx.x;   // 2*1024*48 threads
    int c8 = idx % 48;
    int t  = idx / 48;
    int l  = t & (LL - 1);
    int b  = t >> 10;
    int c0 = c8 * 8;
    int y = l >> 5, x = l & 31;
    const short* vp = kv + CR;
    float acc[8];
    {
        short8 v0 = *(const short8*)&vp[(size_t)(b * LL + l) * 576 + c0];
        #pragma unroll
        for (int i = 0; i < 8; i++) acc[i] = bf2f(v0[i]) + cb[c0 + i];
    }
    #pragma unroll
    for (int ky = 0; ky < 3; ky++) {
        int yy = y + ky - 1; if ((unsigned)yy >= 32) continue;
        #pragma unroll
        for (int kx = 0; kx < 3; kx++) {
            int xx = x + kx - 1; if ((unsigned)xx >= 32) continue;
            short8 nv = *(const short8*)&vp[(size_t)(b * LL + yy * 32 + xx) * 576 + c0];
            #pragma unroll
            for (int i = 0; i < 8; i++)
                acc[i] += bf2f(nv[i]) * cw[(c0 + i) * 9 + ky * 3 + kx];
        }
    }
    short8 ov;
    #pragma unroll
    for (int i = 0; i < 8; i++) ov[i] = f2bf(acc[i]);
    *(short8*)&v2[(size_t)(b * LL + l) * C_ + c0] = ov;
}

// ---------------------------------------------------------------------------
// Build attention-friendly layouts (coalescing-optimized, r5):
//   kpack: [bh][key-block kt][perm row s][j 0..31] — key rows PRE-PERMUTED so
//     attn's kf1 (rows l16) / kf2 (rows 16+l16) are contiguous 1KB wave-loads.
//   v2t:   [bh][kt 0..31][nt 0..2][l16 0..15][32] — V^T tiled so each av load
//     is lane-linear (contiguous 1KB).
// ---------------------------------------------------------------------------
__global__ __launch_bounds__(256) void transp_k(
    const short* __restrict__ v2b, const short* __restrict__ kvb,
    short* __restrict__ v2t, short* __restrict__ kpack)
{
    int tid = threadIdx.x;
    if (blockIdx.x < 256) {
        __shared__ short t_lds[64 * 49];
        int bh = blockIdx.x >> 4, b = bh >> 3, h = bh & 7;
        int l0 = (blockIdx.x & 15) << 6;
        for (int i = tid; i < 64 * 48; i += 256) {
            int dl = i / 48, f = i - dl * 48;
            t_lds[dl * 49 + f] = v2b[(size_t)(b * LL + l0 + dl) * C_ + h * HD + f];
        }
        __syncthreads();
        for (int i = tid; i < 64 * 48; i += 256) {
            int f = i >> 6, dl = i & 63;
            int l = l0 + dl;
            v2t[(size_t)bh * 49152 + (size_t)((l >> 5) * 3 + (f >> 4)) * 512
                + (f & 15) * 32 + (l & 31)] = t_lds[dl * 49 + f];
        }
    } else {
        int gid = (blockIdx.x - 256) * 256 + tid;   // 16*1024*32
        int j = gid & 31, t = gid >> 5;
        int l = t & (LL - 1), bh = t >> 10;
        int b = bh >> 3, h = bh & 7;
        int jj = l & 31, a = jj >> 3, c = jj & 7;
        int s = (c < 4) ? (a * 4 + c) : (16 + a * 4 + (c - 4));
        int lp = (l & ~31) | s;
        kpack[(size_t)bh * 32768 + lp * 32 + j] =
            (j < 24) ? kvb[(size_t)(b * LL + l) * 576 + h * DK + j] : (short)0;
    }
}

// ---------------------------------------------------------------------------
// Flash attention v12: v11 retile (qt=2, grid 2048 blocks = 8/CU) with the
// r4/r5-proven launch_bounds(256,4). r5 occupancy was GRID-limited (1024
// blocks = 4/CU; VGPR=64 allows 8 waves/SIMD) — the retile fixes the grid,
// and qt=2 keeps regs <=~64, so no aggressive reg bound is needed (the
// (256,6) bound was the only compiler-facing novelty in the r6 crash).
// ---------------------------------------------------------------------------
__global__ __launch_bounds__(256, 4) void attn_k(
    const short* __restrict__ qbuf, const short* __restrict__ kpack,
    const short* __restrict__ v2t, short* __restrict__ obuf)
{
    int tid = threadIdx.x;
    int lane = tid & 63, wave = tid >> 6, quad = lane >> 4, l16 = lane & 15;
    int bh = blockIdx.y, b = bh >> 3, h = bh & 7;
    int q0 = blockIdx.x * 128 + wave * 32;

    // Q fragments (2 x 16 queries), pre-scaled by scale*log2(e); k>=24 zero.
    short8 qf[2];
    #pragma unroll
    for (int qt = 0; qt < 2; qt++) {
        short8 z = {0, 0, 0, 0, 0, 0, 0, 0};
        qf[qt] = z;
        if (quad < 3) {
            short8 raw = *(const short8*)&qbuf[(size_t)(b * NPIX + q0 + qt * 16 + l16) * CR + h * DK + quad * 8];
            #pragma unroll
            for (int i = 0; i < 8; i++) qf[qt][i] = f2bf(bf2f(raw[i]) * SCALE_L2E);
        }
    }

    f32x4 z4 = {0.f, 0.f, 0.f, 0.f};
    f32x4 oacc[2][3] = {{z4, z4, z4}, {z4, z4, z4}};
    float rs[2] = {0.f, 0.f};

    // All bases lane-linear: every load below is one contiguous 1KB wave-load.
    const short* kp = kpack + (((size_t)bh) << 15) + l16 * 32 + quad * 8;
    const short* vt = v2t + (size_t)bh * 49152 + l16 * 32 + quad * 8;

    // prefetch K for tile 0
    short8 kf1 = *(const short8*)&kp[0];
    short8 kf2 = *(const short8*)&kp[512];

    for (int kt = 0; kt < 32; kt++) {       // 32 keys per iteration
        // current tile V (consumed after QK+exp -> self-covering)
        short8 av0 = *(const short8*)&vt[(kt * 3) << 9];
        short8 av1 = *(const short8*)&vt[(kt * 3 + 1) << 9];
        short8 av2 = *(const short8*)&vt[(kt * 3 + 2) << 9];
        // prefetch next tile's K (wraparound read harmless)
        int ktn = (kt + 1) & 31;
        short8 nk1 = *(const short8*)&kp[ktn << 10];
        short8 nk2 = *(const short8*)&kp[(ktn << 10) + 512];
        #pragma unroll
        for (int qt = 0; qt < 2; qt++) {
            f32x4 s1 = __builtin_amdgcn_mfma_f32_16x16x32_bf16(kf1, qf[qt], z4, 0, 0, 0);
            f32x4 s2 = __builtin_amdgcn_mfma_f32_16x16x32_bf16(kf2, qf[qt], z4, 0, 0, 0);
            float e0 = exp2b(s1[0]), e1 = exp2b(s1[1]);
            float e2 = exp2b(s1[2]), e3 = exp2b(s1[3]);
            float g0 = exp2b(s2[0]), g1 = exp2b(s2[1]);
            float g2 = exp2b(s2[2]), g3 = exp2b(s2[3]);
            rs[qt] += ((e0 + e1) + (e2 + e3)) + ((g0 + g1) + (g2 + g3));
            union { unsigned u[4]; short8 s; } pb;
            pb.u[0] = cvt_pk_bf16(e0, e1);
            pb.u[1] = cvt_pk_bf16(e2, e3);
            pb.u[2] = cvt_pk_bf16(g0, g1);
            pb.u[3] = cvt_pk_bf16(g2, g3);
            oacc[qt][0] = __builtin_amdgcn_mfma_f32_16x16x32_bf16(av0, pb.s, oacc[qt][0], 0, 0, 0);
            oacc[qt][1] = __builtin_amdgcn_mfma_f32_16x16x32_bf16(av1, pb.s, oacc[qt][1], 0, 0, 0);
            oacc[qt][2] = __builtin_amdgcn_mfma_f32_16x16x32_bf16(av2, pb.s, oacc[qt][2], 0, 0, 0);
        }
        kf1 = nk1; kf2 = nk2;
    }

    #pragma unroll
    for (int qt = 0; qt < 2; qt++) {
        // full denominator for this lane's query l16: sum the 4 quad partials
        float s = rs[qt];
        s += __shfl_xor(s, 16);
        s += __shfl_xor(s, 32);
        float inv = 1.0f / s;
        // O^T: col=query=l16, row=f=nt*16+quad*4+r -> packed 8B stores.
        short* orow = &obuf[(size_t)(b * NPIX + q0 + qt * 16 + l16) * C_ + h * HD + quad * 4];
        #pragma unroll
        for (int nt = 0; nt < 3; nt++) {
            uint2 ov;
            ov.x = cvt_pk_bf16(oacc[qt][nt][0] * inv, oacc[qt][nt][1] * inv);
            ov.y = cvt_pk_bf16(oacc[qt][nt][2] * inv, oacc[qt][nt][3] * inv);
            *(uint2*)&orow[nt * 16] = ov;
        }
    }
}

// ---------------------------------------------------------------------------
extern "C" void kernel_launch(void* const* d_in, const int* in_sizes, int n_in,
                              void* d_out, int out_size, void* d_ws, size_t ws_size,
                              hipStream_t stream)
{
    const float* x      = (const float*)d_in[0];
    const float* red_w1 = (const float*)d_in[1];
    const float* red_b1 = (const float*)d_in[2];
    const float* red_w3 = (const float*)d_in[3];
    const float* red_b3 = (const float*)d_in[4];
    const float* red_w5 = (const float*)d_in[5];
    const float* red_b5 = (const float*)d_in[6];
    const float* fus_w  = (const float*)d_in[7];
    const float* fus_b  = (const float*)d_in[8];
    const float* q_w    = (const float*)d_in[9];
    const float* k_w    = (const float*)d_in[10];
    const float* v_w    = (const float*)d_in[11];
    const float* cpe_w  = (const float*)d_in[12];
    const float* cpe_b  = (const float*)d_in[13];
    const float* proj_w = (const float*)d_in[14];
    const float* proj_b = (const float*)d_in[15];
    float* out = (float*)d_out;

    char* ws = (char*)d_ws;
    short* A_fus = (short*)(ws +         0);  // [2048 x 6144] bf16   25.17 MB (reused as obuf)
    short* obuf  = A_fus;
    float* tmpA  = (float*)(ws +  25165824);  // [2,16384,128] fp32   16.78 MB (reused as qbuf)
    short* qbuf  = (short*)(ws +  25165824);
    float* tmpB  = (float*)(ws +  41943040);  // [2,16384,128] fp32   16.78 MB (reused below)
    float* part  = (float*)(ws +  41943040);  // [4][2048 x 192] fp32  6.29 MB
    short* v2t   = (short*)(ws +  48234496);  // [16][32][3][512] bf16 1.57 MB
    short* kpack = (short*)(ws +  49807360);  // [16][1024][32] bf16   1.05 MB
    short* Wt    = (short*)(ws +  58720256);  // [6144 x 192] bf16     2.36 MB
    short* Bkv   = (short*)(ws +  61079552);  // [192 x 576] bf16      0.22 MB
    short* qw_b  = (short*)(ws +  61300736);  // [384 x 192] bf16      0.15 MB
    short* pw_b  = (short*)(ws +  61448192);  // [384 x 384] bf16      0.29 MB
    short* xr    = (short*)(ws +  61743104);  // [2048 x 192] bf16     0.79 MB
    short* kvb   = (short*)(ws +  62529536);  // [2048 x 576] bf16     2.36 MB
    short* v2b   = (short*)(ws +  64888832);  // [2048 x 384] bf16     1.57 MB
    (void)in_sizes; (void)n_in; (void)out_size; (void)ws_size;

    dim3 blk(256);
    // reduction dwconv chains (4 pixels/thread; final pass writes patch layout)
    dwconv_k<1,1,C_><<<dim3(4096), blk, 0, stream>>>(x,    0,   nullptr, A_fus, 0,   red_w1, red_b1);
    dwconv_k<0,3,C_><<<dim3(4096), blk, 0, stream>>>(x,    128, tmpA,  nullptr, 0,   red_w3, red_b3);
    dwconv_k<1,3,CG><<<dim3(4096), blk, 0, stream>>>(tmpA, 0,   nullptr, A_fus, 128, red_w3, red_b3);
    dwconv_k<0,5,C_><<<dim3(4096), blk, 0, stream>>>(x,    256, tmpB,  nullptr, 0,   red_w5, red_b5);
    dwconv_k<0,5,CG><<<dim3(4096), blk, 0, stream>>>(tmpB, 0,   tmpA,  nullptr, 0,   red_w5, red_b5);
    dwconv_k<1,5,CG><<<dim3(4096), blk, 0, stream>>>(tmpA, 0,   nullptr, A_fus, 256, red_w5, red_b5);
    // weight prep (fp32 -> bf16)
    prep_k<<<dim3(5904), blk, 0, stream>>>(fus_w, k_w, v_w, q_w, proj_w, Wt, Bkv, qw_b, pw_b);
    // fusion conv as split-K=4 GEMM -> fp32 partials -> reduce + bias + GELU
    gemm_part_k<<<dim3(32, 3, 4), blk, 0, stream>>>(A_fus, Wt, part, 2048, CR, KFUS, KFUS / 4);
    fusred_k<<<dim3(1536), blk, 0, stream>>>(part, fus_b, xr);
    // k|v = xr @ [k_w | v_w]  -> kvb [2048 x 576]
    gemm_k<0,0><<<dim3(32, 9), blk, 0, stream>>>(xr, Bkv, kvb, (const float*)nullptr, 2048, 576, CR);
    // v2 = v + cpe dwconv (8 channels/thread)
    cpe_k<<<dim3(384), blk, 0, stream>>>(kvb, cpe_w, cpe_b, v2b);
    // layout prep for attention
    transp_k<<<dim3(2304), blk, 0, stream>>>(v2b, kvb, v2t, kpack);
    // q = x @ q_w -> qbuf [32768 x 192]
    gemm_k<1,0><<<dim3(512, 3), blk, 0, stream>>>(x, qw_b, qbuf, (const float*)nullptr, 32768, CR, C_);
    // flash attention -> obuf [32768 x 384]
    attn_k<<<dim3(128, 16), blk, 0, stream>>>(qbuf, kpack, v2t, obuf);
    // projection -> out (fp32)
    gemm_k<0,1><<<dim3(512, 6), blk, 0, stream>>>(obuf, pw_b, out, proj_b, 32768, C_, C_);
}

// Round 9
// 399.769 us; speedup vs baseline: 1.0485x; 1.0485x over previous
//
#include <hip/hip_runtime.h>
#include <math.h>

typedef short short8 __attribute__((ext_vector_type(8)));
typedef float f32x4 __attribute__((ext_vector_type(4)));

#define B_    2
#define HH    128
#define WW    128
#define NPIX  16384     // H*W
#define C_    384
#define CR    192
#define CG    128
#define NH    8
#define DK    24
#define HD    48
#define LL    1024      // 32*32 reduced tokens
#define KFUS  6144      // 16*384
// (hd*0.5)^-0.5 * log2(e)  — folded so P = exp2(S)
#define SCALE_L2E 0.29448889f

__device__ __forceinline__ float bf2f(short h) {
    union { unsigned u; float f; } v; v.u = ((unsigned)(unsigned short)h) << 16; return v.f;
}
__device__ __forceinline__ short f2bf(float f) {          // RNE
    union { float f; unsigned u; } v; v.f = f;
    unsigned r = v.u + 0x7fffu + ((v.u >> 16) & 1u);
    return (short)(unsigned short)(r >> 16);
}
__device__ __forceinline__ short f2bf_fast(float f) {     // round-nearest, ties-away
    union { float f; unsigned u; } v; v.f = f;
    return (short)(unsigned short)((v.u + 0x8000u) >> 16);
}
// 2^x via compiler-emitted v_exp_f32 (TRANS hazard handled by compiler;
// raw inline-asm v_exp_f32 caused nondeterministic stale reads in r2).
__device__ __forceinline__ float exp2b(float x) {
#if __has_builtin(__builtin_amdgcn_exp2f)
    return __builtin_amdgcn_exp2f(x);
#else
    return exp2f(x);
#endif
}
// pack bf16(lo) | bf16(hi) in one instruction (RNE). No builtin on gfx950.
// Regular VALU op (not TRANS) — guide T12 recipe, asm->MFMA path refcheck'd.
__device__ __forceinline__ unsigned cvt_pk_bf16(float lo, float hi) {
    unsigned r;
    asm("v_cvt_pk_bf16_f32 %0, %1, %2" : "=v"(r) : "v"(lo), "v"(hi));
    return r;
}

// ---------------------------------------------------------------------------
// Depthwise conv body, one 128-channel group, 4 x-pixels per thread.
// PATCH=0: fp32 flat out [B,NPIX,128].
// PATCH=1: bf16 im2col patch layout for the 4x4/stride4 conv.
// ---------------------------------------------------------------------------
template<int PATCH, int KS, int STRIDE>
__device__ __forceinline__ void dwconv_body(
    int idx,
    const float* __restrict__ in, int in_off,
    float* __restrict__ outf, short* __restrict__ outp, int out_coff,
    const float* __restrict__ w, const float* __restrict__ bias)
{
    constexpr int pad = KS / 2;
    constexpr int NV = 4 + KS - 1;
    int c    = idx & (CG - 1);
    int pix4 = (idx >> 7) & 4095;
    int b    = idx >> 19;
    int y = pix4 >> 5, x0 = (pix4 & 31) << 2;
    float wl[KS * KS];
    #pragma unroll
    for (int i = 0; i < KS * KS; i++) wl[i] = w[c * KS * KS + i];
    float bv = bias[c];
    float acc[4] = {bv, bv, bv, bv};
    #pragma unroll
    for (int ky = 0; ky < KS; ky++) {
        int yy = y + ky - pad;
        if ((unsigned)yy >= HH) continue;
        const float* rowp = &in[(size_t)(b * NPIX + yy * WW) * STRIDE + in_off + c];
        float v[NV];
        #pragma unroll
        for (int j = 0; j < NV; j++) {
            int xx = x0 + j - pad;
            v[j] = ((unsigned)xx < WW) ? rowp[(size_t)xx * STRIDE] : 0.f;
        }
        #pragma unroll
        for (int kx = 0; kx < KS; kx++)
            #pragma unroll
            for (int o = 0; o < 4; o++)
                acc[o] += v[o + kx] * wl[ky * KS + kx];
    }
    if (!PATCH) {
        float* op = &outf[(size_t)(b * NPIX + y * WW + x0) * CG + c];
        #pragma unroll
        for (int o = 0; o < 4; o++) op[(size_t)o * CG] = acc[o];
    } else {
        int m = b * LL + (y >> 2) * 32 + (x0 >> 2);
        short* op = &outp[(size_t)m * KFUS + ((y & 3) * 4) * C_ + out_coff + c];
        #pragma unroll
        for (int o = 0; o < 4; o++) op[(size_t)o * C_] = f2bf(acc[o]);
    }
}

template<int PATCH, int KS, int STRIDE>
__global__ __launch_bounds__(256) void dwconv_k(
    const float* __restrict__ in, int in_off,
    float* __restrict__ outf, short* __restrict__ outp, int out_coff,
    const float* __restrict__ w, const float* __restrict__ bias)
{
    dwconv_body<PATCH, KS, STRIDE>(blockIdx.x * 256 + threadIdx.x,
                                   in, in_off, outf, outp, out_coff, w, bias);
}

// ---------------------------------------------------------------------------
// Weight prep body (fp32 -> bf16)
// ---------------------------------------------------------------------------
__device__ __forceinline__ void prep_body(
    int idx,
    const float* __restrict__ fus_w, const float* __restrict__ k_w,
    const float* __restrict__ v_w, const float* __restrict__ q_w,
    const float* __restrict__ proj_w,
    short* __restrict__ Wt, short* __restrict__ Bkv,
    short* __restrict__ qw_b, short* __restrict__ pw_b)
{
    const int NW = KFUS * CR;        // 1179648
    if (idx < NW) {
        int k = idx / CR, oc = idx - k * CR;
        int p = k / C_,  ic = k - p * C_;
        Wt[idx] = f2bf(fus_w[(oc * C_ + ic) * 16 + p]);
        return;
    }
    idx -= NW;
    if (idx < CR * 576) {            // 110592
        int k = idx / 576, n = idx - k * 576;
        Bkv[idx] = f2bf((n < CR) ? k_w[k * CR + n] : v_w[k * C_ + (n - CR)]);
        return;
    }
    idx -= CR * 576;
    if (idx < C_ * CR) { qw_b[idx] = f2bf(q_w[idx]); return; }
    idx -= C_ * CR;
    if (idx < C_ * C_) pw_b[idx] = f2bf(proj_w[idx]);
}

// ---------------------------------------------------------------------------
// Fused stage 1: the three independent first-pass dwconvs + weight prep.
// All four branches read/write disjoint buffers — safe in one launch.
// blocks [0,4096): dw1x1 -> A_fus patch cols 0..127
//        [4096,8192): dw3x3 pass1 -> tmpA
//        [8192,12288): dw5x5 pass1 -> tmpB
//        [12288,18192): weight prep
// ---------------------------------------------------------------------------
__global__ __launch_bounds__(256) void stage1_k(
    const float* __restrict__ x, short* __restrict__ A_fus,
    float* __restrict__ tmpA, float* __restrict__ tmpB,
    const float* __restrict__ red_w1, const float* __restrict__ red_b1,
    const float* __restrict__ red_w3, const float* __restrict__ red_b3,
    const float* __restrict__ red_w5, const float* __restrict__ red_b5,
    const float* __restrict__ fus_w, const float* __restrict__ k_w,
    const float* __restrict__ v_w, const float* __restrict__ q_w,
    const float* __restrict__ proj_w,
    short* __restrict__ Wt, short* __restrict__ Bkv,
    short* __restrict__ qw_b, short* __restrict__ pw_b)
{
    int bx = blockIdx.x;
    if (bx < 4096) {
        dwconv_body<1,1,C_>(bx * 256 + threadIdx.x, x, 0, nullptr, A_fus, 0, red_w1, red_b1);
    } else if (bx < 8192) {
        dwconv_body<0,3,C_>((bx - 4096) * 256 + threadIdx.x, x, 128, tmpA, nullptr, 0, red_w3, red_b3);
    } else if (bx < 12288) {
        dwconv_body<0,5,C_>((bx - 8192) * 256 + threadIdx.x, x, 256, tmpB, nullptr, 0, red_w5, red_b5);
    } else {
        prep_body((bx - 12288) * 256 + threadIdx.x, fus_w, k_w, v_w, q_w, proj_w, Wt, Bkv, qw_b, pw_b);
    }
}

// ---------------------------------------------------------------------------
// Generic bf16 MFMA GEMM: C[M,N] = A[M,K] * B[K,N] (+bias)
// AF=1: A fp32 (converted on stage). CF=1: C written fp32.
// SWAP=1: M-tile from blockIdx.y, N-tile from blockIdx.x — so the blocks
// sharing an A block-row dispatch consecutively (x-major) and the A-row is
// served from L2/L3 instead of per-pass HBM re-streams.
// ---------------------------------------------------------------------------
template<int AF, int CF, int SWAP = 0>
__global__ __launch_bounds__(256) void gemm_k(
    const void* __restrict__ Av, const short* __restrict__ Bm, void* __restrict__ Cv,
    const float* __restrict__ bias, int M, int N, int K)
{
    __shared__ short a_lds[64 * 40];
    __shared__ short bT_lds[64 * 40];
    int tid = threadIdx.x;
    int lane = tid & 63, wave = tid >> 6, quad = lane >> 4, l16 = lane & 15;
    int bm = (SWAP ? blockIdx.y : blockIdx.x) * 64;
    int bn = (SWAP ? blockIdx.x : blockIdx.y) * 64;
    int wm = (wave >> 1) * 32, wn = (wave & 1) * 32;
    f32x4 z4 = {0.f, 0.f, 0.f, 0.f};
    f32x4 acc00 = z4, acc01 = z4, acc10 = z4, acc11 = z4;
    int arow = tid >> 2, aseg = tid & 3;
    int bk = tid >> 3, bnseg = tid & 7;

    for (int k0 = 0; k0 < K; k0 += 32) {
        __syncthreads();
        if (AF) {
            const float* Af = (const float*)Av;
            const float4* p = (const float4*)&Af[(size_t)(bm + arow) * K + k0 + aseg * 8];
            float4 f0 = p[0], f1 = p[1];
            short8 av;
            av[0] = f2bf_fast(f0.x); av[1] = f2bf_fast(f0.y);
            av[2] = f2bf_fast(f0.z); av[3] = f2bf_fast(f0.w);
            av[4] = f2bf_fast(f1.x); av[5] = f2bf_fast(f1.y);
            av[6] = f2bf_fast(f1.z); av[7] = f2bf_fast(f1.w);
            *(short8*)&a_lds[arow * 40 + aseg * 8] = av;
        } else {
            const short* Ab = (const short*)Av;
            *(short8*)&a_lds[arow * 40 + aseg * 8] =
                *(const short8*)&Ab[(size_t)(bm + arow) * K + k0 + aseg * 8];
        }
        short8 bv = *(const short8*)&Bm[(size_t)(k0 + bk) * N + bn + bnseg * 8];
        #pragma unroll
        for (int i = 0; i < 8; i++) bT_lds[(bnseg * 8 + i) * 40 + bk] = bv[i];
        __syncthreads();
        short8 a0 = *(short8*)&a_lds[(wm + l16) * 40 + quad * 8];
        short8 a1 = *(short8*)&a_lds[(wm + 16 + l16) * 40 + quad * 8];
        short8 b0 = *(short8*)&bT_lds[(wn + l16) * 40 + quad * 8];
        short8 b1 = *(short8*)&bT_lds[(wn + 16 + l16) * 40 + quad * 8];
        acc00 = __builtin_amdgcn_mfma_f32_16x16x32_bf16(a0, b0, acc00, 0, 0, 0);
        acc01 = __builtin_amdgcn_mfma_f32_16x16x32_bf16(a0, b1, acc01, 0, 0, 0);
        acc10 = __builtin_amdgcn_mfma_f32_16x16x32_bf16(a1, b0, acc10, 0, 0, 0);
        acc11 = __builtin_amdgcn_mfma_f32_16x16x32_bf16(a1, b1, acc11, 0, 0, 0);
    }
    f32x4 accs[2][2] = {{acc00, acc01}, {acc10, acc11}};
    #pragma unroll
    for (int mt = 0; mt < 2; mt++)
      #pragma unroll
      for (int nt = 0; nt < 2; nt++) {
        int col = bn + wn + nt * 16 + l16;
        float bvv = bias ? bias[col] : 0.f;
        #pragma unroll
        for (int r = 0; r < 4; r++) {
            int row = bm + wm + mt * 16 + quad * 4 + r;
            float v = accs[mt][nt][r] + bvv;
            if (CF) ((float*)Cv)[(size_t)row * N + col] = v;
            else    ((short*)Cv)[(size_t)row * N + col] = f2bf(v);
        }
      }
}

// ---------------------------------------------------------------------------
// Split-K GEMM for the fusion conv: fp32 partials per z-slice.
// N-tile in blockIdx.x (3 tiles) so A-row-sharing blocks dispatch together.
// ---------------------------------------------------------------------------
__global__ __launch_bounds__(256) void gemm_part_k(
    const short* __restrict__ A, const short* __restrict__ Bm,
    float* __restrict__ Cpart, int M, int N, int K, int kchunk)
{
    __shared__ short a_lds[64 * 40];
    __shared__ short bT_lds[64 * 40];
    int tid = threadIdx.x;
    int lane = tid & 63, wave = tid >> 6, quad = lane >> 4, l16 = lane & 15;
    int bm = blockIdx.y * 64, bn = blockIdx.x * 64;
    int kbeg = blockIdx.z * kchunk, kend = kbeg + kchunk;
    int wm = (wave >> 1) * 32, wn = (wave & 1) * 32;
    f32x4 z4 = {0.f, 0.f, 0.f, 0.f};
    f32x4 acc00 = z4, acc01 = z4, acc10 = z4, acc11 = z4;
    int arow = tid >> 2, aseg = tid & 3;
    int bk = tid >> 3, bnseg = tid & 7;

    for (int k0 = kbeg; k0 < kend; k0 += 32) {
        __syncthreads();
        *(short8*)&a_lds[arow * 40 + aseg * 8] =
            *(const short8*)&A[(size_t)(bm + arow) * K + k0 + aseg * 8];
        short8 bv = *(const short8*)&Bm[(size_t)(k0 + bk) * N + bn + bnseg * 8];
        #pragma unroll
        for (int i = 0; i < 8; i++) bT_lds[(bnseg * 8 + i) * 40 + bk] = bv[i];
        __syncthreads();
        short8 a0 = *(short8*)&a_lds[(wm + l16) * 40 + quad * 8];
        short8 a1 = *(short8*)&a_lds[(wm + 16 + l16) * 40 + quad * 8];
        short8 b0 = *(short8*)&bT_lds[(wn + l16) * 40 + quad * 8];
        short8 b1 = *(short8*)&bT_lds[(wn + 16 + l16) * 40 + quad * 8];
        acc00 = __builtin_amdgcn_mfma_f32_16x16x32_bf16(a0, b0, acc00, 0, 0, 0);
        acc01 = __builtin_amdgcn_mfma_f32_16x16x32_bf16(a0, b1, acc01, 0, 0, 0);
        acc10 = __builtin_amdgcn_mfma_f32_16x16x32_bf16(a1, b0, acc10, 0, 0, 0);
        acc11 = __builtin_amdgcn_mfma_f32_16x16x32_bf16(a1, b1, acc11, 0, 0, 0);
    }
    float* Cs = Cpart + (size_t)blockIdx.z * M * N;
    f32x4 accs[2][2] = {{acc00, acc01}, {acc10, acc11}};
    #pragma unroll
    for (int mt = 0; mt < 2; mt++)
      #pragma unroll
      for (int nt = 0; nt < 2; nt++) {
        int col = bn + wn + nt * 16 + l16;
        #pragma unroll
        for (int r = 0; r < 4; r++) {
            int row = bm + wm + mt * 16 + quad * 4 + r;
            Cs[(size_t)row * N + col] = accs[mt][nt][r];
        }
      }
}

// Reduce 4 split-K partials + bias + exact GELU -> bf16 xr [2048 x 192]
__global__ __launch_bounds__(256) void fusred_k(
    const float* __restrict__ part, const float* __restrict__ bias,
    short* __restrict__ xr)
{
    const int MN = 2048 * CR;
    int idx = blockIdx.x * 256 + threadIdx.x;
    float v = part[idx] + part[idx + MN] + part[idx + 2 * MN] + part[idx + 3 * MN]
            + bias[idx % CR];
    v = 0.5f * v * (1.f + erff(v * 0.70710678118f));
    xr[idx] = f2bf(v);
}

// ---------------------------------------------------------------------------
// CPE: v2[b,l,c] = v[b,l,c] + dwconv3x3(v as [B,C,32,32])[b,c,l] + cpe_b[c]
// Vectorized 8 channels/thread (short8 loads — consecutive c contiguous).
// ---------------------------------------------------------------------------
__global__ __launch_bounds__(256) void cpe_k(
    const short* __restrict__ kv, const float* __restrict__ cw,
    const float* __restrict__ cb, short* __restrict__ v2)
{
    int idx = blockIdx.x * 256 + threadIdx.x;   // 2*1024*48 threads
    int c8 = idx % 48;
    int t  = idx / 48;
    int l  = t & (LL - 1);
    int b  = t >> 10;
    int c0 = c8 * 8;
    int y = l >> 5, x = l & 31;
    const short* vp = kv + CR;
    float acc[8];
    {
        short8 v0 = *(const short8*)&vp[(size_t)(b * LL + l) * 576 + c0];
        #pragma unroll
        for (int i = 0; i < 8; i++) acc[i] = bf2f(v0[i]) + cb[c0 + i];
    }
    #pragma unroll
    for (int ky = 0; ky < 3; ky++) {
        int yy = y + ky - 1; if ((unsigned)yy >= 32) continue;
        #pragma unroll
        for (int kx = 0; kx < 3; kx++) {
            int xx = x + kx - 1; if ((unsigned)xx >= 32) continue;
            short8 nv = *(const short8*)&vp[(size_t)(b * LL + yy * 32 + xx) * 576 + c0];
            #pragma unroll
            for (int i = 0; i < 8; i++)
                acc[i] += bf2f(nv[i]) * cw[(c0 + i) * 9 + ky * 3 + kx];
        }
    }
    short8 ov;
    #pragma unroll
    for (int i = 0; i < 8; i++) ov[i] = f2bf(acc[i]);
    *(short8*)&v2[(size_t)(b * LL + l) * C_ + c0] = ov;
}

// ---------------------------------------------------------------------------
// Build attention-friendly layouts (r5-verified):
//   kpack: [bh][key-block kt][perm row s][j 0..31] — key rows PRE-PERMUTED so
//     attn's kf1 (rows l16) / kf2 (rows 16+l16) are contiguous 1KB wave-loads.
//   v2t:   [bh][kt 0..31][nt 0..2][l16 0..15][32] — V^T tiled so each av load
//     is lane-linear (contiguous 1KB).
// ---------------------------------------------------------------------------
__global__ __launch_bounds__(256) void transp_k(
    const short* __restrict__ v2b, const short* __restrict__ kvb,
    short* __restrict__ v2t, short* __restrict__ kpack)
{
    int tid = threadIdx.x;
    if (blockIdx.x < 256) {
        __shared__ short t_lds[64 * 49];
        int bh = blockIdx.x >> 4, b = bh >> 3, h = bh & 7;
        int l0 = (blockIdx.x & 15) << 6;
        for (int i = tid; i < 64 * 48; i += 256) {
            int dl = i / 48, f = i - dl * 48;
            t_lds[dl * 49 + f] = v2b[(size_t)(b * LL + l0 + dl) * C_ + h * HD + f];
        }
        __syncthreads();
        for (int i = tid; i < 64 * 48; i += 256) {
            int f = i >> 6, dl = i & 63;
            int l = l0 + dl;
            v2t[(size_t)bh * 49152 + (size_t)((l >> 5) * 3 + (f >> 4)) * 512
                + (f & 15) * 32 + (l & 31)] = t_lds[dl * 49 + f];
        }
    } else {
        int gid = (blockIdx.x - 256) * 256 + tid;   // 16*1024*32
        int j = gid & 31, t = gid >> 5;
        int l = t & (LL - 1), bh = t >> 10;
        int b = bh >> 3, h = bh & 7;
        int jj = l & 31, a = jj >> 3, c = jj & 7;
        int s = (c < 4) ? (a * 4 + c) : (16 + a * 4 + (c - 4));
        int lp = (l & ~31) | s;
        kpack[(size_t)bh * 32768 + lp * 32 + j] =
            (j < 24) ? kvb[(size_t)(b * LL + l) * 576 + h * DK + j] : (short)0;
    }
}

// ---------------------------------------------------------------------------
// Flash attention v10 (r5-verified, best passing: 68us): zero-LDS permuted-K
// + fully coalesced loads (producer-side permutation) + 5-load 1-deep
// prefetch. qt=4 (64 queries/wave) so each wave streams its head's K/V once.
// ---------------------------------------------------------------------------
__global__ __launch_bounds__(256, 4) void attn_k(
    const short* __restrict__ qbuf, const short* __restrict__ kpack,
    const short* __restrict__ v2t, short* __restrict__ obuf)
{
    int tid = threadIdx.x;
    int lane = tid & 63, wave = tid >> 6, quad = lane >> 4, l16 = lane & 15;
    int bh = blockIdx.y, b = bh >> 3, h = bh & 7;
    int q0 = blockIdx.x * 256 + wave * 64;

    // Q fragments (4 x 16 queries), pre-scaled by scale*log2(e); k>=24 zero.
    short8 qf[4];
    #pragma unroll
    for (int qt = 0; qt < 4; qt++) {
        short8 z = {0, 0, 0, 0, 0, 0, 0, 0};
        qf[qt] = z;
        if (quad < 3) {
            short8 raw = *(const short8*)&qbuf[(size_t)(b * NPIX + q0 + qt * 16 + l16) * CR + h * DK + quad * 8];
            #pragma unroll
            for (int i = 0; i < 8; i++) qf[qt][i] = f2bf(bf2f(raw[i]) * SCALE_L2E);
        }
    }

    f32x4 z4 = {0.f, 0.f, 0.f, 0.f};
    f32x4 oacc[4][3] = {{z4, z4, z4}, {z4, z4, z4}, {z4, z4, z4}, {z4, z4, z4}};
    float rs[4] = {0.f, 0.f, 0.f, 0.f};

    // All bases are lane-linear: each load below covers one contiguous 1KB.
    const short* kp = kpack + (((size_t)bh) << 15) + l16 * 32 + quad * 8;
    const short* vt = v2t + (size_t)bh * 49152 + l16 * 32 + quad * 8;

    // prefetch tile 0
    short8 kf1 = *(const short8*)&kp[0];
    short8 kf2 = *(const short8*)&kp[512];
    short8 av0 = *(const short8*)&vt[0];
    short8 av1 = *(const short8*)&vt[512];
    short8 av2 = *(const short8*)&vt[1024];

    for (int kt = 0; kt < 32; kt++) {       // 32 keys per iteration
        int ktn = (kt + 1) & 31;            // wraparound read is harmless
        short8 nk1 = *(const short8*)&kp[ktn << 10];
        short8 nk2 = *(const short8*)&kp[(ktn << 10) + 512];
        short8 nv0 = *(const short8*)&vt[(ktn * 3) << 9];
        short8 nv1 = *(const short8*)&vt[((ktn * 3 + 1)) << 9];
        short8 nv2 = *(const short8*)&vt[((ktn * 3 + 2)) << 9];
        #pragma unroll
        for (int qt = 0; qt < 4; qt++) {
            f32x4 s1 = __builtin_amdgcn_mfma_f32_16x16x32_bf16(kf1, qf[qt], z4, 0, 0, 0);
            f32x4 s2 = __builtin_amdgcn_mfma_f32_16x16x32_bf16(kf2, qf[qt], z4, 0, 0, 0);
            float e0 = exp2b(s1[0]), e1 = exp2b(s1[1]);
            float e2 = exp2b(s1[2]), e3 = exp2b(s1[3]);
            float g0 = exp2b(s2[0]), g1 = exp2b(s2[1]);
            float g2 = exp2b(s2[2]), g3 = exp2b(s2[3]);
            rs[qt] += ((e0 + e1) + (e2 + e3)) + ((g0 + g1) + (g2 + g3));
            union { unsigned u[4]; short8 s; } pb;
            pb.u[0] = cvt_pk_bf16(e0, e1);
            pb.u[1] = cvt_pk_bf16(e2, e3);
            pb.u[2] = cvt_pk_bf16(g0, g1);
            pb.u[3] = cvt_pk_bf16(g2, g3);
            oacc[qt][0] = __builtin_amdgcn_mfma_f32_16x16x32_bf16(av0, pb.s, oacc[qt][0], 0, 0, 0);
            oacc[qt][1] = __builtin_amdgcn_mfma_f32_16x16x32_bf16(av1, pb.s, oacc[qt][1], 0, 0, 0);
            oacc[qt][2] = __builtin_amdgcn_mfma_f32_16x16x32_bf16(av2, pb.s, oacc[qt][2], 0, 0, 0);
        }
        kf1 = nk1; kf2 = nk2; av0 = nv0; av1 = nv1; av2 = nv2;
    }

    #pragma unroll
    for (int qt = 0; qt < 4; qt++) {
        // full denominator for this lane's query l16: sum the 4 quad partials
        float s = rs[qt];
        s += __shfl_xor(s, 16);
        s += __shfl_xor(s, 32);
        float inv = 1.0f / s;
        // O^T: col=query=l16, row=f=nt*16+quad*4+r -> packed 8B stores.
        short* orow = &obuf[(size_t)(b * NPIX + q0 + qt * 16 + l16) * C_ + h * HD + quad * 4];
        #pragma unroll
        for (int nt = 0; nt < 3; nt++) {
            uint2 ov;
            ov.x = cvt_pk_bf16(oacc[qt][nt][0] * inv, oacc[qt][nt][1] * inv);
            ov.y = cvt_pk_bf16(oacc[qt][nt][2] * inv, oacc[qt][nt][3] * inv);
            *(uint2*)&orow[nt * 16] = ov;
        }
    }
}

// ---------------------------------------------------------------------------
extern "C" void kernel_launch(void* const* d_in, const int* in_sizes, int n_in,
                              void* d_out, int out_size, void* d_ws, size_t ws_size,
                              hipStream_t stream)
{
    const float* x      = (const float*)d_in[0];
    const float* red_w1 = (const float*)d_in[1];
    const float* red_b1 = (const float*)d_in[2];
    const float* red_w3 = (const float*)d_in[3];
    const float* red_b3 = (const float*)d_in[4];
    const float* red_w5 = (const float*)d_in[5];
    const float* red_b5 = (const float*)d_in[6];
    const float* fus_w  = (const float*)d_in[7];
    const float* fus_b  = (const float*)d_in[8];
    const float* q_w    = (const float*)d_in[9];
    const float* k_w    = (const float*)d_in[10];
    const float* v_w    = (const float*)d_in[11];
    const float* cpe_w  = (const float*)d_in[12];
    const float* cpe_b  = (const float*)d_in[13];
    const float* proj_w = (const float*)d_in[14];
    const float* proj_b = (const float*)d_in[15];
    float* out = (float*)d_out;

    char* ws = (char*)d_ws;
    short* A_fus = (short*)(ws +         0);  // [2048 x 6144] bf16   25.17 MB (reused as obuf)
    short* obuf  = A_fus;
    float* tmpA  = (float*)(ws +  25165824);  // [2,16384,128] fp32   16.78 MB (reused as qbuf)
    short* qbuf  = (short*)(ws +  25165824);
    float* tmpB  = (float*)(ws +  41943040);  // [2,16384,128] fp32   16.78 MB (reused below)
    float* part  = (float*)(ws +  41943040);  // [4][2048 x 192] fp32  6.29 MB
    short* v2t   = (short*)(ws +  48234496);  // [16][32][3][512] bf16 1.57 MB
    short* kpack = (short*)(ws +  49807360);  // [16][1024][32] bf16   1.05 MB
    short* Wt    = (short*)(ws +  58720256);  // [6144 x 192] bf16     2.36 MB
    short* Bkv   = (short*)(ws +  61079552);  // [192 x 576] bf16      0.22 MB
    short* qw_b  = (short*)(ws +  61300736);  // [384 x 192] bf16      0.15 MB
    short* pw_b  = (short*)(ws +  61448192);  // [384 x 384] bf16      0.29 MB
    short* xr    = (short*)(ws +  61743104);  // [2048 x 192] bf16     0.79 MB
    short* kvb   = (short*)(ws +  62529536);  // [2048 x 576] bf16     2.36 MB
    short* v2b   = (short*)(ws +  64888832);  // [2048 x 384] bf16     1.57 MB
    (void)in_sizes; (void)n_in; (void)out_size; (void)ws_size;

    dim3 blk(256);
    // fused: dw1x1 + dw3x3-pass1 + dw5x5-pass1 + weight prep (independent)
    stage1_k<<<dim3(18192), blk, 0, stream>>>(
        x, A_fus, tmpA, tmpB, red_w1, red_b1, red_w3, red_b3, red_w5, red_b5,
        fus_w, k_w, v_w, q_w, proj_w, Wt, Bkv, qw_b, pw_b);
    // remaining dwconv chain passes (sequential deps)
    dwconv_k<1,3,CG><<<dim3(4096), blk, 0, stream>>>(tmpA, 0, nullptr, A_fus, 128, red_w3, red_b3);
    dwconv_k<0,5,CG><<<dim3(4096), blk, 0, stream>>>(tmpB, 0, tmpA,  nullptr, 0,   red_w5, red_b5);
    dwconv_k<1,5,CG><<<dim3(4096), blk, 0, stream>>>(tmpA, 0, nullptr, A_fus, 256, red_w5, red_b5);
    // fusion conv as split-K=4 GEMM -> fp32 partials -> reduce + bias + GELU
    gemm_part_k<<<dim3(3, 32, 4), blk, 0, stream>>>(A_fus, Wt, part, 2048, CR, KFUS, KFUS / 4);
    fusred_k<<<dim3(1536), blk, 0, stream>>>(part, fus_b, xr);
    // k|v = xr @ [k_w | v_w]  -> kvb [2048 x 576]
    gemm_k<0,0><<<dim3(32, 9), blk, 0, stream>>>(xr, Bkv, kvb, (const float*)nullptr, 2048, 576, CR);
    // v2 = v + cpe dwconv (8 channels/thread)
    cpe_k<<<dim3(384), blk, 0, stream>>>(kvb, cpe_w, cpe_b, v2b);
    // layout prep for attention
    transp_k<<<dim3(2304), blk, 0, stream>>>(v2b, kvb, v2t, kpack);
    // q = x @ q_w -> qbuf [32768 x 192]  (N-tiles in x for A-row L2 reuse)
    gemm_k<1,0,1><<<dim3(3, 512), blk, 0, stream>>>(x, qw_b, qbuf, (const float*)nullptr, 32768, CR, C_);
    // flash attention -> obuf [32768 x 384]
    attn_k<<<dim3(64, 16), blk, 0, stream>>>(qbuf, kpack, v2t, obuf);
    // projection -> out (fp32)  (N-tiles in x for A-row L2 reuse)
    gemm_k<0,1,1><<<dim3(6, 512), blk, 0, stream>>>(obuf, pw_b, out, proj_b, 32768, C_, C_);
}

// Round 10
// 361.949 us; speedup vs baseline: 1.1581x; 1.1045x over previous
//
#include <hip/hip_runtime.h>
#include <math.h>

typedef short short8 __attribute__((ext_vector_type(8)));
typedef float f32x4 __attribute__((ext_vector_type(4)));

#define B_    2
#define HH    128
#define WW    128
#define NPIX  16384     // H*W
#define C_    384
#define CR    192
#define CG    128
#define NH    8
#define DK    24
#define HD    48
#define LL    1024      // 32*32 reduced tokens
#define KFUS  6144      // 16*384
// (hd*0.5)^-0.5 * log2(e)  — folded so P = exp2(S)
#define SCALE_L2E 0.29448889f

__device__ __forceinline__ float bf2f(short h) {
    union { unsigned u; float f; } v; v.u = ((unsigned)(unsigned short)h) << 16; return v.f;
}
__device__ __forceinline__ short f2bf(float f) {          // RNE
    union { float f; unsigned u; } v; v.f = f;
    unsigned r = v.u + 0x7fffu + ((v.u >> 16) & 1u);
    return (short)(unsigned short)(r >> 16);
}
__device__ __forceinline__ short f2bf_fast(float f) {     // round-nearest, ties-away
    union { float f; unsigned u; } v; v.f = f;
    return (short)(unsigned short)((v.u + 0x8000u) >> 16);
}
// 2^x via compiler-emitted v_exp_f32 (TRANS hazard handled by compiler;
// raw inline-asm v_exp_f32 caused nondeterministic stale reads in r2).
__device__ __forceinline__ float exp2b(float x) {
#if __has_builtin(__builtin_amdgcn_exp2f)
    return __builtin_amdgcn_exp2f(x);
#else
    return exp2f(x);
#endif
}
// pack bf16(lo) | bf16(hi) in one instruction (RNE). No builtin on gfx950.
// Regular VALU op (not TRANS) — guide T12 recipe, asm->MFMA path refcheck'd.
__device__ __forceinline__ unsigned cvt_pk_bf16(float lo, float hi) {
    unsigned r;
    asm("v_cvt_pk_bf16_f32 %0, %1, %2" : "=v"(r) : "v"(lo), "v"(hi));
    return r;
}

// ---------------------------------------------------------------------------
// Depthwise conv, one 128-channel group, 4 x-pixels per thread (x0 % 4 == 0).
// PATCH=0: fp32 flat out [B,NPIX,128].
// PATCH=1: bf16 im2col patch layout for the 4x4/stride4 conv.
// ---------------------------------------------------------------------------
template<int PATCH, int KS, int STRIDE>
__global__ __launch_bounds__(256) void dwconv_k(
    const float* __restrict__ in, int in_off,
    float* __restrict__ outf, short* __restrict__ outp, int out_coff,
    const float* __restrict__ w, const float* __restrict__ bias)
{
    constexpr int pad = KS / 2;
    constexpr int NV = 4 + KS - 1;
    int idx = blockIdx.x * 256 + threadIdx.x;   // 2*4096*128 total
    int c    = idx & (CG - 1);
    int pix4 = (idx >> 7) & 4095;
    int b    = idx >> 19;
    int y = pix4 >> 5, x0 = (pix4 & 31) << 2;
    float wl[KS * KS];
    #pragma unroll
    for (int i = 0; i < KS * KS; i++) wl[i] = w[c * KS * KS + i];
    float bv = bias[c];
    float acc[4] = {bv, bv, bv, bv};
    #pragma unroll
    for (int ky = 0; ky < KS; ky++) {
        int yy = y + ky - pad;
        if ((unsigned)yy >= HH) continue;
        const float* rowp = &in[(size_t)(b * NPIX + yy * WW) * STRIDE + in_off + c];
        float v[NV];
        #pragma unroll
        for (int j = 0; j < NV; j++) {
            int xx = x0 + j - pad;
            v[j] = ((unsigned)xx < WW) ? rowp[(size_t)xx * STRIDE] : 0.f;
        }
        #pragma unroll
        for (int kx = 0; kx < KS; kx++)
            #pragma unroll
            for (int o = 0; o < 4; o++)
                acc[o] += v[o + kx] * wl[ky * KS + kx];
    }
    if (!PATCH) {
        float* op = &outf[(size_t)(b * NPIX + y * WW + x0) * CG + c];
        #pragma unroll
        for (int o = 0; o < 4; o++) op[(size_t)o * CG] = acc[o];
    } else {
        int m = b * LL + (y >> 2) * 32 + (x0 >> 2);
        short* op = &outp[(size_t)m * KFUS + ((y & 3) * 4) * C_ + out_coff + c];
        #pragma unroll
        for (int o = 0; o < 4; o++) op[(size_t)o * C_] = f2bf(acc[o]);
    }
}

// ---------------------------------------------------------------------------
// Weight prep (fp32 -> bf16), TRANSPOSED outputs (r10): all GEMM B matrices
// are stored BT[N][K] so the GEMM's B staging is a contiguous short8 load +
// one ds_write_b128 (replaces the 8-scalar-LDS-write in-kernel transpose).
// Writes are coalesced (consecutive idx -> consecutive K); reads strided but
// one-time (~6MB).
// ---------------------------------------------------------------------------
__global__ __launch_bounds__(256) void prep_k(
    const float* __restrict__ fus_w, const float* __restrict__ k_w,
    const float* __restrict__ v_w, const float* __restrict__ q_w,
    const float* __restrict__ proj_w,
    short* __restrict__ WtT, short* __restrict__ BkvT,
    short* __restrict__ qw_bT, short* __restrict__ pw_bT)
{
    int idx = blockIdx.x * 256 + threadIdx.x;
    const int NW = KFUS * CR;        // 1179648
    if (idx < NW) {
        int oc = idx / KFUS, k = idx - oc * KFUS;   // WtT[oc][k]
        int p = k / C_,  ic = k - p * C_;
        WtT[idx] = f2bf(fus_w[(oc * C_ + ic) * 16 + p]);
        return;
    }
    idx -= NW;
    if (idx < CR * 576) {            // BkvT[n 0..575][k 0..191]
        int n = idx / CR, k = idx - n * CR;
        BkvT[idx] = f2bf((n < CR) ? k_w[k * CR + n] : v_w[k * C_ + (n - CR)]);
        return;
    }
    idx -= CR * 576;
    if (idx < C_ * CR) {             // qw_bT[n 0..191][k 0..383]
        int n = idx / C_, k = idx - n * C_;
        qw_bT[idx] = f2bf(q_w[k * CR + n]);
        return;
    }
    idx -= C_ * CR;
    if (idx < C_ * C_) {             // pw_bT[n 0..383][k 0..383]
        int n = idx / C_, k = idx - n * C_;
        pw_bT[idx] = f2bf(proj_w[k * C_ + n]);
    }
}

// ---------------------------------------------------------------------------
// Generic bf16 MFMA GEMM: C[M,N] = A[M,K] * BT^T[K,N] (+bias), B given as
// BT[N][K]. Both A and B stage as contiguous short8 -> ds_write_b128; LDS
// tile contents identical to the old in-kernel-transpose version.
// AF=1: A fp32 (converted on stage). CF=1: C written fp32.
// ---------------------------------------------------------------------------
template<int AF, int CF>
__global__ __launch_bounds__(256) void gemm_k(
    const void* __restrict__ Av, const short* __restrict__ BT, void* __restrict__ Cv,
    const float* __restrict__ bias, int M, int N, int K)
{
    __shared__ short a_lds[64 * 40];
    __shared__ short bT_lds[64 * 40];
    int tid = threadIdx.x;
    int lane = tid & 63, wave = tid >> 6, quad = lane >> 4, l16 = lane & 15;
    int bm = blockIdx.x * 64, bn = blockIdx.y * 64;
    int wm = (wave >> 1) * 32, wn = (wave & 1) * 32;
    f32x4 z4 = {0.f, 0.f, 0.f, 0.f};
    f32x4 acc00 = z4, acc01 = z4, acc10 = z4, acc11 = z4;
    int arow = tid >> 2, aseg = tid & 3;

    for (int k0 = 0; k0 < K; k0 += 32) {
        __syncthreads();
        if (AF) {
            const float* Af = (const float*)Av;
            const float4* p = (const float4*)&Af[(size_t)(bm + arow) * K + k0 + aseg * 8];
            float4 f0 = p[0], f1 = p[1];
            short8 av;
            av[0] = f2bf_fast(f0.x); av[1] = f2bf_fast(f0.y);
            av[2] = f2bf_fast(f0.z); av[3] = f2bf_fast(f0.w);
            av[4] = f2bf_fast(f1.x); av[5] = f2bf_fast(f1.y);
            av[6] = f2bf_fast(f1.z); av[7] = f2bf_fast(f1.w);
            *(short8*)&a_lds[arow * 40 + aseg * 8] = av;
        } else {
            const short* Ab = (const short*)Av;
            *(short8*)&a_lds[arow * 40 + aseg * 8] =
                *(const short8*)&Ab[(size_t)(bm + arow) * K + k0 + aseg * 8];
        }
        *(short8*)&bT_lds[arow * 40 + aseg * 8] =
            *(const short8*)&BT[(size_t)(bn + arow) * K + k0 + aseg * 8];
        __syncthreads();
        short8 a0 = *(short8*)&a_lds[(wm + l16) * 40 + quad * 8];
        short8 a1 = *(short8*)&a_lds[(wm + 16 + l16) * 40 + quad * 8];
        short8 b0 = *(short8*)&bT_lds[(wn + l16) * 40 + quad * 8];
        short8 b1 = *(short8*)&bT_lds[(wn + 16 + l16) * 40 + quad * 8];
        acc00 = __builtin_amdgcn_mfma_f32_16x16x32_bf16(a0, b0, acc00, 0, 0, 0);
        acc01 = __builtin_amdgcn_mfma_f32_16x16x32_bf16(a0, b1, acc01, 0, 0, 0);
        acc10 = __builtin_amdgcn_mfma_f32_16x16x32_bf16(a1, b0, acc10, 0, 0, 0);
        acc11 = __builtin_amdgcn_mfma_f32_16x16x32_bf16(a1, b1, acc11, 0, 0, 0);
    }
    f32x4 accs[2][2] = {{acc00, acc01}, {acc10, acc11}};
    #pragma unroll
    for (int mt = 0; mt < 2; mt++)
      #pragma unroll
      for (int nt = 0; nt < 2; nt++) {
        int col = bn + wn + nt * 16 + l16;
        float bvv = bias ? bias[col] : 0.f;
        #pragma unroll
        for (int r = 0; r < 4; r++) {
            int row = bm + wm + mt * 16 + quad * 4 + r;
            float v = accs[mt][nt][r] + bvv;
            if (CF) ((float*)Cv)[(size_t)row * N + col] = v;
            else    ((short*)Cv)[(size_t)row * N + col] = f2bf(v);
        }
      }
}

// ---------------------------------------------------------------------------
// Split-K GEMM for the fusion conv (B as BT[N][K]): fp32 partials per z.
// ---------------------------------------------------------------------------
__global__ __launch_bounds__(256) void gemm_part_k(
    const short* __restrict__ A, const short* __restrict__ BT,
    float* __restrict__ Cpart, int M, int N, int K, int kchunk)
{
    __shared__ short a_lds[64 * 40];
    __shared__ short bT_lds[64 * 40];
    int tid = threadIdx.x;
    int lane = tid & 63, wave = tid >> 6, quad = lane >> 4, l16 = lane & 15;
    int bm = blockIdx.x * 64, bn = blockIdx.y * 64;
    int kbeg = blockIdx.z * kchunk, kend = kbeg + kchunk;
    int wm = (wave >> 1) * 32, wn = (wave & 1) * 32;
    f32x4 z4 = {0.f, 0.f, 0.f, 0.f};
    f32x4 acc00 = z4, acc01 = z4, acc10 = z4, acc11 = z4;
    int arow = tid >> 2, aseg = tid & 3;

    for (int k0 = kbeg; k0 < kend; k0 += 32) {
        __syncthreads();
        *(short8*)&a_lds[arow * 40 + aseg * 8] =
            *(const short8*)&A[(size_t)(bm + arow) * K + k0 + aseg * 8];
        *(short8*)&bT_lds[arow * 40 + aseg * 8] =
            *(const short8*)&BT[(size_t)(bn + arow) * K + k0 + aseg * 8];
        __syncthreads();
        short8 a0 = *(short8*)&a_lds[(wm + l16) * 40 + quad * 8];
        short8 a1 = *(short8*)&a_lds[(wm + 16 + l16) * 40 + quad * 8];
        short8 b0 = *(short8*)&bT_lds[(wn + l16) * 40 + quad * 8];
        short8 b1 = *(short8*)&bT_lds[(wn + 16 + l16) * 40 + quad * 8];
        acc00 = __builtin_amdgcn_mfma_f32_16x16x32_bf16(a0, b0, acc00, 0, 0, 0);
        acc01 = __builtin_amdgcn_mfma_f32_16x16x32_bf16(a0, b1, acc01, 0, 0, 0);
        acc10 = __builtin_amdgcn_mfma_f32_16x16x32_bf16(a1, b0, acc10, 0, 0, 0);
        acc11 = __builtin_amdgcn_mfma_f32_16x16x32_bf16(a1, b1, acc11, 0, 0, 0);
    }
    float* Cs = Cpart + (size_t)blockIdx.z * M * N;
    f32x4 accs[2][2] = {{acc00, acc01}, {acc10, acc11}};
    #pragma unroll
    for (int mt = 0; mt < 2; mt++)
      #pragma unroll
      for (int nt = 0; nt < 2; nt++) {
        int col = bn + wn + nt * 16 + l16;
        #pragma unroll
        for (int r = 0; r < 4; r++) {
            int row = bm + wm + mt * 16 + quad * 4 + r;
            Cs[(size_t)row * N + col] = accs[mt][nt][r];
        }
      }
}

// Reduce 4 split-K partials + bias + exact GELU -> bf16 xr [2048 x 192]
__global__ __launch_bounds__(256) void fusred_k(
    const float* __restrict__ part, const float* __restrict__ bias,
    short* __restrict__ xr)
{
    const int MN = 2048 * CR;
    int idx = blockIdx.x * 256 + threadIdx.x;
    float v = part[idx] + part[idx + MN] + part[idx + 2 * MN] + part[idx + 3 * MN]
            + bias[idx % CR];
    v = 0.5f * v * (1.f + erff(v * 0.70710678118f));
    xr[idx] = f2bf(v);
}

// ---------------------------------------------------------------------------
// CPE: v2[b,l,c] = v[b,l,c] + dwconv3x3(v as [B,C,32,32])[b,c,l] + cpe_b[c]
// Vectorized 8 channels/thread (short8 loads — consecutive c contiguous).
// ---------------------------------------------------------------------------
__global__ __launch_bounds__(256) void cpe_k(
    const short* __restrict__ kv, const float* __restrict__ cw,
    const float* __restrict__ cb, short* __restrict__ v2)
{
    int idx = blockIdx.x * 256 + threadIdx.x;   // 2*1024*48 threads
    int c8 = idx % 48;
    int t  = idx / 48;
    int l  = t & (LL - 1);
    int b  = t >> 10;
    int c0 = c8 * 8;
    int y = l >> 5, x = l & 31;
    const short* vp = kv + CR;
    float acc[8];
    {
        short8 v0 = *(const short8*)&vp[(size_t)(b * LL + l) * 576 + c0];
        #pragma unroll
        for (int i = 0; i < 8; i++) acc[i] = bf2f(v0[i]) + cb[c0 + i];
    }
    #pragma unroll
    for (int ky = 0; ky < 3; ky++) {
        int yy = y + ky - 1; if ((unsigned)yy >= 32) continue;
        #pragma unroll
        for (int kx = 0; kx < 3; kx++) {
            int xx = x + kx - 1; if ((unsigned)xx >= 32) continue;
            short8 nv = *(const short8*)&vp[(size_t)(b * LL + yy * 32 + xx) * 576 + c0];
            #pragma unroll
            for (int i = 0; i < 8; i++)
                acc[i] += bf2f(nv[i]) * cw[(c0 + i) * 9 + ky * 3 + kx];
        }
    }
    short8 ov;
    #pragma unroll
    for (int i = 0; i < 8; i++) ov[i] = f2bf(acc[i]);
    *(short8*)&v2[(size_t)(b * LL + l) * C_ + c0] = ov;
}

// ---------------------------------------------------------------------------
// Build attention-friendly layouts (r5-verified):
//   kpack: [bh][key-block kt][perm row s][j 0..31] — key rows PRE-PERMUTED so
//     attn's kf1 (rows l16) / kf2 (rows 16+l16) are contiguous 1KB wave-loads.
//   v2t:   [bh][kt 0..31][nt 0..2][l16 0..15][32] — V^T tiled so each av load
//     is lane-linear (contiguous 1KB).
// ---------------------------------------------------------------------------
__global__ __launch_bounds__(256) void transp_k(
    const short* __restrict__ v2b, const short* __restrict__ kvb,
    short* __restrict__ v2t, short* __restrict__ kpack)
{
    int tid = threadIdx.x;
    if (blockIdx.x < 256) {
        __shared__ short t_lds[64 * 49];
        int bh = blockIdx.x >> 4, b = bh >> 3, h = bh & 7;
        int l0 = (blockIdx.x & 15) << 6;
        for (int i = tid; i < 64 * 48; i += 256) {
            int dl = i / 48, f = i - dl * 48;
            t_lds[dl * 49 + f] = v2b[(size_t)(b * LL + l0 + dl) * C_ + h * HD + f];
        }
        __syncthreads();
        for (int i = tid; i < 64 * 48; i += 256) {
            int f = i >> 6, dl = i & 63;
            int l = l0 + dl;
            v2t[(size_t)bh * 49152 + (size_t)((l >> 5) * 3 + (f >> 4)) * 512
                + (f & 15) * 32 + (l & 31)] = t_lds[dl * 49 + f];
        }
    } else {
        int gid = (blockIdx.x - 256) * 256 + tid;   // 16*1024*32
        int j = gid & 31, t = gid >> 5;
        int l = t & (LL - 1), bh = t >> 10;
        int b = bh >> 3, h = bh & 7;
        int jj = l & 31, a = jj >> 3, c = jj & 7;
        int s = (c < 4) ? (a * 4 + c) : (16 + a * 4 + (c - 4));
        int lp = (l & ~31) | s;
        kpack[(size_t)bh * 32768 + lp * 32 + j] =
            (j < 24) ? kvb[(size_t)(b * LL + l) * 576 + h * DK + j] : (short)0;
    }
}

// ---------------------------------------------------------------------------
// Flash attention v10 (r5-verified, best passing: 68us): zero-LDS permuted-K
// + fully coalesced loads (producer-side permutation) + 5-load 1-deep
// prefetch. qt=4 (64 queries/wave) so each wave streams its head's K/V once.
// ---------------------------------------------------------------------------
__global__ __launch_bounds__(256, 4) void attn_k(
    const short* __restrict__ qbuf, const short* __restrict__ kpack,
    const short* __restrict__ v2t, short* __restrict__ obuf)
{
    int tid = threadIdx.x;
    int lane = tid & 63, wave = tid >> 6, quad = lane >> 4, l16 = lane & 15;
    int bh = blockIdx.y, b = bh >> 3, h = bh & 7;
    int q0 = blockIdx.x * 256 + wave * 64;

    // Q fragments (4 x 16 queries), pre-scaled by scale*log2(e); k>=24 zero.
    short8 qf[4];
    #pragma unroll
    for (int qt = 0; qt < 4; qt++) {
        short8 z = {0, 0, 0, 0, 0, 0, 0, 0};
        qf[qt] = z;
        if (quad < 3) {
            short8 raw = *(const short8*)&qbuf[(size_t)(b * NPIX + q0 + qt * 16 + l16) * CR + h * DK + quad * 8];
            #pragma unroll
            for (int i = 0; i < 8; i++) qf[qt][i] = f2bf(bf2f(raw[i]) * SCALE_L2E);
        }
    }

    f32x4 z4 = {0.f, 0.f, 0.f, 0.f};
    f32x4 oacc[4][3] = {{z4, z4, z4}, {z4, z4, z4}, {z4, z4, z4}, {z4, z4, z4}};
    float rs[4] = {0.f, 0.f, 0.f, 0.f};

    // All bases are lane-linear: each load below covers one contiguous 1KB.
    const short* kp = kpack + (((size_t)bh) << 15) + l16 * 32 + quad * 8;
    const short* vt = v2t + (size_t)bh * 49152 + l16 * 32 + quad * 8;

    // prefetch tile 0
    short8 kf1 = *(const short8*)&kp[0];
    short8 kf2 = *(const short8*)&kp[512];
    short8 av0 = *(const short8*)&vt[0];
    short8 av1 = *(const short8*)&vt[512];
    short8 av2 = *(const short8*)&vt[1024];

    for (int kt = 0; kt < 32; kt++) {       // 32 keys per iteration
        int ktn = (kt + 1) & 31;            // wraparound read is harmless
        short8 nk1 = *(const short8*)&kp[ktn << 10];
        short8 nk2 = *(const short8*)&kp[(ktn << 10) + 512];
        short8 nv0 = *(const short8*)&vt[(ktn * 3) << 9];
        short8 nv1 = *(const short8*)&vt[((ktn * 3 + 1)) << 9];
        short8 nv2 = *(const short8*)&vt[((ktn * 3 + 2)) << 9];
        #pragma unroll
        for (int qt = 0; qt < 4; qt++) {
            f32x4 s1 = __builtin_amdgcn_mfma_f32_16x16x32_bf16(kf1, qf[qt], z4, 0, 0, 0);
            f32x4 s2 = __builtin_amdgcn_mfma_f32_16x16x32_bf16(kf2, qf[qt], z4, 0, 0, 0);
            float e0 = exp2b(s1[0]), e1 = exp2b(s1[1]);
            float e2 = exp2b(s1[2]), e3 = exp2b(s1[3]);
            float g0 = exp2b(s2[0]), g1 = exp2b(s2[1]);
            float g2 = exp2b(s2[2]), g3 = exp2b(s2[3]);
            rs[qt] += ((e0 + e1) + (e2 + e3)) + ((g0 + g1) + (g2 + g3));
            union { unsigned u[4]; short8 s; } pb;
            pb.u[0] = cvt_pk_bf16(e0, e1);
            pb.u[1] = cvt_pk_bf16(e2, e3);
            pb.u[2] = cvt_pk_bf16(g0, g1);
            pb.u[3] = cvt_pk_bf16(g2, g3);
            oacc[qt][0] = __builtin_amdgcn_mfma_f32_16x16x32_bf16(av0, pb.s, oacc[qt][0], 0, 0, 0);
            oacc[qt][1] = __builtin_amdgcn_mfma_f32_16x16x32_bf16(av1, pb.s, oacc[qt][1], 0, 0, 0);
            oacc[qt][2] = __builtin_amdgcn_mfma_f32_16x16x32_bf16(av2, pb.s, oacc[qt][2], 0, 0, 0);
        }
        kf1 = nk1; kf2 = nk2; av0 = nv0; av1 = nv1; av2 = nv2;
    }

    #pragma unroll
    for (int qt = 0; qt < 4; qt++) {
        // full denominator for this lane's query l16: sum the 4 quad partials
        float s = rs[qt];
        s += __shfl_xor(s, 16);
        s += __shfl_xor(s, 32);
        float inv = 1.0f / s;
        // O^T: col=query=l16, row=f=nt*16+quad*4+r -> packed 8B stores.
        short* orow = &obuf[(size_t)(b * NPIX + q0 + qt * 16 + l16) * C_ + h * HD + quad * 4];
        #pragma unroll
        for (int nt = 0; nt < 3; nt++) {
            uint2 ov;
            ov.x = cvt_pk_bf16(oacc[qt][nt][0] * inv, oacc[qt][nt][1] * inv);
            ov.y = cvt_pk_bf16(oacc[qt][nt][2] * inv, oacc[qt][nt][3] * inv);
            *(uint2*)&orow[nt * 16] = ov;
        }
    }
}

// ---------------------------------------------------------------------------
extern "C" void kernel_launch(void* const* d_in, const int* in_sizes, int n_in,
                              void* d_out, int out_size, void* d_ws, size_t ws_size,
                              hipStream_t stream)
{
    const float* x      = (const float*)d_in[0];
    const float* red_w1 = (const float*)d_in[1];
    const float* red_b1 = (const float*)d_in[2];
    const float* red_w3 = (const float*)d_in[3];
    const float* red_b3 = (const float*)d_in[4];
    const float* red_w5 = (const float*)d_in[5];
    const float* red_b5 = (const float*)d_in[6];
    const float* fus_w  = (const float*)d_in[7];
    const float* fus_b  = (const float*)d_in[8];
    const float* q_w    = (const float*)d_in[9];
    const float* k_w    = (const float*)d_in[10];
    const float* v_w    = (const float*)d_in[11];
    const float* cpe_w  = (const float*)d_in[12];
    const float* cpe_b  = (const float*)d_in[13];
    const float* proj_w = (const float*)d_in[14];
    const float* proj_b = (const float*)d_in[15];
    float* out = (float*)d_out;

    char* ws = (char*)d_ws;
    short* A_fus = (short*)(ws +         0);  // [2048 x 6144] bf16   25.17 MB (reused as obuf)
    short* obuf  = A_fus;
    float* tmpA  = (float*)(ws +  25165824);  // [2,16384,128] fp32   16.78 MB (reused as qbuf)
    short* qbuf  = (short*)(ws +  25165824);
    float* tmpB  = (float*)(ws +  41943040);  // [2,16384,128] fp32   16.78 MB (reused below)
    float* part  = (float*)(ws +  41943040);  // [4][2048 x 192] fp32  6.29 MB
    short* v2t   = (short*)(ws +  48234496);  // [16][32][3][512] bf16 1.57 MB
    short* kpack = (short*)(ws +  49807360);  // [16][1024][32] bf16   1.05 MB
    short* WtT   = (short*)(ws +  58720256);  // [192 x 6144] bf16     2.36 MB
    short* BkvT  = (short*)(ws +  61079552);  // [576 x 192] bf16      0.22 MB
    short* qw_bT = (short*)(ws +  61300736);  // [192 x 384] bf16      0.15 MB
    short* pw_bT = (short*)(ws +  61448192);  // [384 x 384] bf16      0.29 MB
    short* xr    = (short*)(ws +  61743104);  // [2048 x 192] bf16     0.79 MB
    short* kvb   = (short*)(ws +  62529536);  // [2048 x 576] bf16     2.36 MB
    short* v2b   = (short*)(ws +  64888832);  // [2048 x 384] bf16     1.57 MB
    (void)in_sizes; (void)n_in; (void)out_size; (void)ws_size;

    dim3 blk(256);
    // reduction dwconv chains (4 pixels/thread; final pass writes patch layout)
    dwconv_k<1,1,C_><<<dim3(4096), blk, 0, stream>>>(x,    0,   nullptr, A_fus, 0,   red_w1, red_b1);
    dwconv_k<0,3,C_><<<dim3(4096), blk, 0, stream>>>(x,    128, tmpA,  nullptr, 0,   red_w3, red_b3);
    dwconv_k<1,3,CG><<<dim3(4096), blk, 0, stream>>>(tmpA, 0,   nullptr, A_fus, 128, red_w3, red_b3);
    dwconv_k<0,5,C_><<<dim3(4096), blk, 0, stream>>>(x,    256, tmpB,  nullptr, 0,   red_w5, red_b5);
    dwconv_k<0,5,CG><<<dim3(4096), blk, 0, stream>>>(tmpB, 0,   tmpA,  nullptr, 0,   red_w5, red_b5);
    dwconv_k<1,5,CG><<<dim3(4096), blk, 0, stream>>>(tmpA, 0,   nullptr, A_fus, 256, red_w5, red_b5);
    // weight prep (fp32 -> bf16, transposed B layouts)
    prep_k<<<dim3(5904), blk, 0, stream>>>(fus_w, k_w, v_w, q_w, proj_w, WtT, BkvT, qw_bT, pw_bT);
    // fusion conv as split-K=4 GEMM -> fp32 partials -> reduce + bias + GELU
    gemm_part_k<<<dim3(32, 3, 4), blk, 0, stream>>>(A_fus, WtT, part, 2048, CR, KFUS, KFUS / 4);
    fusred_k<<<dim3(1536), blk, 0, stream>>>(part, fus_b, xr);
    // k|v = xr @ [k_w | v_w]  -> kvb [2048 x 576]
    gemm_k<0,0><<<dim3(32, 9), blk, 0, stream>>>(xr, BkvT, kvb, (const float*)nullptr, 2048, 576, CR);
    // v2 = v + cpe dwconv (8 channels/thread)
    cpe_k<<<dim3(384), blk, 0, stream>>>(kvb, cpe_w, cpe_b, v2b);
    // layout prep for attention
    transp_k<<<dim3(2304), blk, 0, stream>>>(v2b, kvb, v2t, kpack);
    // q = x @ q_w -> qbuf [32768 x 192]
    gemm_k<1,0><<<dim3(512, 3), blk, 0, stream>>>(x, qw_bT, qbuf, (const float*)nullptr, 32768, CR, C_);
    // flash attention -> obuf [32768 x 384]
    attn_k<<<dim3(64, 16), blk, 0, stream>>>(qbuf, kpack, v2t, obuf);
    // projection -> out (fp32)
    gemm_k<0,1><<<dim3(512, 6), blk, 0, stream>>>(obuf, pw_bT, out, proj_b, 32768, C_, C_);
}